// Round 5
// baseline (96.030 us; speedup 1.0000x reference)
//
#include <hip/hip_runtime.h>

// B=16, N=2048, S=SO=12, K=32.
// out[b,i,k,s] = softmax_k( leaky_relu( e_src[b,i] + e_dst[b,j] ) ) * x[b,j,s],  j=idx[b,i,k]
//
// Round-5 probe: HIGH OCCUPANCY variant. 256-thread blocks, 8 pairs/block,
// 2 KB LDS -> ~6-8 waves/SIMD (vs round 3/4's 1 block/CU, 4 waves/SIMD).
// Keeps every validated component:
//  - single launch, no workspace,
//  - per-wave wvec via __shfl (no wvec barrier)          [round 4],
//  - softmax without max-subtract, guard at 80           [rounds 1-4],
//  - fully dense remapped global stores                  [round 3],
// and returns the data-dependent row gather to L1/L2 (x is 1.5 MB,
// L2-resident; rounds 0-2 showed this gather is cheap).

#define GAT_N 2048
#define GAT_ALPHA 0.5f

__global__ __launch_bounds__(256) void gat_hi(
    const float* __restrict__ x,    // [B*N, 12]
    const float* __restrict__ W,    // [12,12]
    const float* __restrict__ a,    // [24]
    const int*   __restrict__ idx,  // [B*N, 32]
    float*       __restrict__ out)  // [B*N, 32, 12]
{
    __shared__ float att_tab[8 * 32];   // per-(pair,k) attention
    __shared__ int   j_tab[8 * 32];     // per-(pair,k) neighbor id

    const int tid  = threadIdx.x;
    const int slot = tid >> 5;                 // pair slot 0..7
    const int k    = tid & 31;                 // neighbor slot
    const int pair = blockIdx.x * 8 + slot;    // b*N + i
    const int base = pair & ~(GAT_N - 1);      // b*N

    // ---- prefetch: idx, neighbor row, own row ----
    const int j   = idx[(size_t)pair * 32 + k];
    const int nbr = base + j;

    const float4* rowj = (const float4*)(x + (size_t)nbr * 12);
    const float4 n0 = rowj[0], n1 = rowj[1], n2 = rowj[2];
    const float4* rowi = (const float4*)(x + (size_t)pair * 12);
    const float4 i0 = rowi[0], i1 = rowi[1], i2 = rowi[2];

    // ---- per-wave wvec: lanes l%24 compute W·a, consumers shfl-broadcast ----
    float acc;
    {
        const int l     = tid & 63;
        const int id24  = l % 24;
        const int s     = id24 % 12;
        const float* av = a + (id24 < 12 ? 0 : 12);
        acc = 0.f;
        #pragma unroll
        for (int t = 0; t < 12; ++t) acc += W[s * 12 + t] * av[t];
    }
    float ws[12], wd[12];
    #pragma unroll
    for (int s = 0; s < 12; ++s) {
        ws[s] = __shfl(acc, s, 64);
        wd[s] = __shfl(acc, 12 + s, 64);
    }

    const float e_src =
        i0.x*ws[0] + i0.y*ws[1] + i0.z*ws[2]  + i0.w*ws[3] +
        i1.x*ws[4] + i1.y*ws[5] + i1.z*ws[6]  + i1.w*ws[7] +
        i2.x*ws[8] + i2.y*ws[9] + i2.z*ws[10] + i2.w*ws[11];
    const float e_dst =
        n0.x*wd[0] + n0.y*wd[1] + n0.z*wd[2]  + n0.w*wd[3] +
        n1.x*wd[4] + n1.y*wd[5] + n1.z*wd[6]  + n1.w*wd[7] +
        n2.x*wd[8] + n2.y*wd[9] + n2.z*wd[10] + n2.w*wd[11];

    // ---- leaky_relu + softmax over 32 lanes (no max-subtract, guarded) ----
    float e = e_src + e_dst;
    e = e > 0.f ? e : GAT_ALPHA * e;
    const float ex = __expf(fminf(e, 80.f));
    float sum = ex;
    #pragma unroll
    for (int off = 16; off; off >>= 1) sum += __shfl_xor(sum, off, 32);
    const float att = ex / sum;

    att_tab[slot * 32 + k] = att;
    j_tab[slot * 32 + k]   = j;
    __syncthreads();

    // ---- fully dense stores: block region = 8*96 = 768 float4, 3/thread ----
    float4* o4 = (float4*)out + (size_t)blockIdx.x * 768;
    #pragma unroll
    for (int r = 0; r < 3; ++r) {
        const int f   = tid + 256 * r;
        const int pl  = f / 96;          // owning pair slot
        const int rem = f - 96 * pl;
        const int kk  = rem / 3;         // owning neighbor slot
        const int q   = rem - 3 * kk;    // float4 word within row
        const float attk = att_tab[pl * 32 + kk];
        const int   jk   = j_tab[pl * 32 + kk];
        const float4 v = *((const float4*)(x + (size_t)(base + jk) * 12) + q);
        o4[f] = make_float4(attk * v.x, attk * v.y, attk * v.z, attk * v.w);
    }
}

// ---------------- Fallback: verified generic single-kernel path ----------------
__global__ __launch_bounds__(256) void gat_fused(
    const float* __restrict__ x, const float* __restrict__ W,
    const float* __restrict__ a, const int* __restrict__ idx,
    float* __restrict__ out)
{
    __shared__ float wvec[24];
    __shared__ float stage[8 * 384];
    const int tid = threadIdx.x;

    if (tid < 24) {
        const int s = tid % 12;
        const float* av = a + (tid < 12 ? 0 : 12);
        float acc = 0.f;
        #pragma unroll
        for (int t = 0; t < 12; ++t) acc += W[s * 12 + t] * av[t];
        wvec[tid] = acc;
    }
    __syncthreads();

    const int p    = tid >> 5;
    const int pair = blockIdx.x * 8 + p;
    const int k    = tid & 31;

    const float4* rowi = (const float4*)(x + (size_t)pair * 12);
    const float4 i0 = rowi[0], i1 = rowi[1], i2 = rowi[2];
    const float e_src =
        i0.x*wvec[0] + i0.y*wvec[1] + i0.z*wvec[2]  + i0.w*wvec[3] +
        i1.x*wvec[4] + i1.y*wvec[5] + i1.z*wvec[6]  + i1.w*wvec[7] +
        i2.x*wvec[8] + i2.y*wvec[9] + i2.z*wvec[10] + i2.w*wvec[11];

    const int j   = idx[(size_t)pair * 32 + k];
    const int nbr = (pair & ~(GAT_N - 1)) + j;
    const float4* rowj = (const float4*)(x + (size_t)nbr * 12);
    const float4 n0 = rowj[0], n1 = rowj[1], n2 = rowj[2];
    const float e_dst =
        n0.x*wvec[12] + n0.y*wvec[13] + n0.z*wvec[14] + n0.w*wvec[15] +
        n1.x*wvec[16] + n1.y*wvec[17] + n1.z*wvec[18] + n1.w*wvec[19] +
        n2.x*wvec[20] + n2.y*wvec[21] + n2.z*wvec[22] + n2.w*wvec[23];

    float sc = e_src + e_dst;
    sc = sc > 0.f ? sc : GAT_ALPHA * sc;
    float m = sc;
    #pragma unroll
    for (int off = 16; off; off >>= 1) m = fmaxf(m, __shfl_xor(m, off, 32));
    const float ex = __expf(sc - m);
    float sum = ex;
    #pragma unroll
    for (int off = 16; off; off >>= 1) sum += __shfl_xor(sum, off, 32);
    const float att = ex / sum;

    float4* st = (float4*)(stage + p * 384 + k * 12);
    st[0] = make_float4(att * n0.x, att * n0.y, att * n0.z, att * n0.w);
    st[1] = make_float4(att * n1.x, att * n1.y, att * n1.z, att * n1.w);
    st[2] = make_float4(att * n2.x, att * n2.y, att * n2.z, att * n2.w);
    __syncthreads();

    const float4* sm4 = (const float4*)stage;
    float4* o4 = (float4*)(out + (size_t)blockIdx.x * 8 * 384);
    #pragma unroll
    for (int r = 0; r < 3; ++r) o4[tid + 256 * r] = sm4[tid + 256 * r];
}

extern "C" void kernel_launch(void* const* d_in, const int* in_sizes, int n_in,
                              void* d_out, int out_size, void* d_ws, size_t ws_size,
                              hipStream_t stream) {
    // inputs: fushed_features (unused), input_data, W, a, idx
    const float* x   = (const float*)d_in[1];
    const float* W   = (const float*)d_in[2];
    const float* a   = (const float*)d_in[3];
    const int*   idx = (const int*)d_in[4];
    float* out = (float*)d_out;

    const int pairs = in_sizes[1] / 12;    // B*N = 32768 nodes

    if ((pairs & (GAT_N - 1)) == 0) {
        gat_hi<<<pairs / 8, 256, 0, stream>>>(x, W, a, idx, out);
    } else {
        gat_fused<<<pairs / 8, 256, 0, stream>>>(x, W, a, idx, out);
    }
}

// Round 6
// 87.731 us; speedup vs baseline: 1.0946x; 1.0946x over previous
//
#include <hip/hip_runtime.h>

// B=16, N=2048, S=SO=12, K=32.
// out[b,i,k,s] = softmax_k( leaky_relu( es[b,i] + ed[b,j] ) ) * x[b,j,s],  j=idx[b,i,k]
//
// Round-6: validated R4 dataflow (f32 LDS row table + edt, one barrier, shfl
// wvec, no-max softmax, dense remapped stores) restructured for block-level
// pipelining:
//  - 512 blocks x 512 threads, 64 pairs/block, same 104 KB LDS -> each CU runs
//    two blocks in SUCCESSION: block n+1's global staging overlaps block n's
//    store drain (R4's grid==CU-count left write BW idle during staging),
//  - 8-wave barrier (half the straggler slack of R4's 16-wave),
//  - XCD-affinity swizzle: blockIdx%8 (the XCD round-robin residue) selects
//    batch = 2*xcd + hi, so each XCD's L2 serves exactly 2 batches of x
//    (3 MB, fits the 4 MB per-XCD L2) instead of streaming 24 MB from L3.

#define GAT_N 2048
#define GAT_ALPHA 0.5f
#define PPBLK 64       // pairs per block
#define THREADS 512

__global__ __launch_bounds__(THREADS) void gat_lds2(
    const float* __restrict__ x,    // [B*N, 12]
    const float* __restrict__ W,    // [12,12]
    const float* __restrict__ a,    // [24]
    const int*   __restrict__ idx,  // [B*N, 32]
    float*       __restrict__ out,  // [B*N, 32, 12]
    const int    swz)               // 1: XCD-affinity block mapping
{
    __shared__ float rows[GAT_N * 12];   // 96 KB: full row table of this batch
    __shared__ float edt[GAT_N];         // 8 KB: per-node dst logits
    __shared__ float es_loc[PPBLK];      // this block's per-pair src logits

    const int tid = threadIdx.x;
    int b, blk32;
    if (swz) {
        // 512 blocks: xcd residue -> batch pair, so each XCD reads 2 batches
        const int xcd = blockIdx.x & 7;
        const int i   = blockIdx.x >> 3;         // 0..63
        b     = (xcd << 1) | (i >> 5);           // batch 0..15
        blk32 = i & 31;                          // block-in-batch 0..31
    } else {
        b     = blockIdx.x >> 5;
        blk32 = blockIdx.x & 31;
    }

    const int slot   = tid >> 5;                 // pair slot 0..15
    const int k      = tid & 31;                 // neighbor slot
    const int pairG0 = b * GAT_N + blk32 * PPBLK + slot;

    // ---- prefetch idx for 4 tasks (pairs slot+16t) ----
    int jv[4];
    #pragma unroll
    for (int t = 0; t < 4; ++t)
        jv[t] = idx[(size_t)(pairG0 + 16 * t) * 32 + k];

    // ---- per-wave wvec: lanes l%24 compute W·a, all threads shfl-broadcast ----
    float acc;
    {
        const int l     = tid & 63;
        const int id24  = l % 24;
        const int s     = id24 % 12;
        const float* av = a + (id24 < 12 ? 0 : 12);
        acc = 0.f;
        #pragma unroll
        for (int t = 0; t < 12; ++t) acc += W[s * 12 + t] * av[t];
    }
    float ws[12], wd[12];
    #pragma unroll
    for (int s = 0; s < 12; ++s) {
        ws[s] = __shfl(acc, s, 64);
        wd[s] = __shfl(acc, 12 + s, 64);
    }

    // ---- stage 4 rows/thread in 2 chunks of 2 rows (keeps VGPR low);
    //      compute ed (always) and es (block's own rows) from registers ----
    const bool own_es = (tid >> 4) == blk32;     // 16 threads own the block's 64 rows
    #pragma unroll
    for (int c = 0; c < 2; ++c) {
        const float4* gp = (const float4*)(x + (size_t)b * GAT_N * 12
                                             + (size_t)tid * 48 + c * 24);
        const float4 v0 = gp[0], v1 = gp[1], v2 = gp[2];
        const float4 v3 = gp[3], v4 = gp[4], v5 = gp[5];

        const float ed0 =
            v0.x*wd[0] + v0.y*wd[1] + v0.z*wd[2]  + v0.w*wd[3] +
            v1.x*wd[4] + v1.y*wd[5] + v1.z*wd[6]  + v1.w*wd[7] +
            v2.x*wd[8] + v2.y*wd[9] + v2.z*wd[10] + v2.w*wd[11];
        const float ed1 =
            v3.x*wd[0] + v3.y*wd[1] + v3.z*wd[2]  + v3.w*wd[3] +
            v4.x*wd[4] + v4.y*wd[5] + v4.z*wd[6]  + v4.w*wd[7] +
            v5.x*wd[8] + v5.y*wd[9] + v5.z*wd[10] + v5.w*wd[11];

        const int nb = 4 * tid + 2 * c;          // first of this chunk's 2 rows
        float4* lp = (float4*)(rows + (size_t)nb * 12);
        lp[0] = v0; lp[1] = v1; lp[2] = v2;
        lp[3] = v3; lp[4] = v4; lp[5] = v5;
        *(float2*)(edt + nb) = make_float2(ed0, ed1);

        if (own_es) {
            const float es0 =
                v0.x*ws[0] + v0.y*ws[1] + v0.z*ws[2]  + v0.w*ws[3] +
                v1.x*ws[4] + v1.y*ws[5] + v1.z*ws[6]  + v1.w*ws[7] +
                v2.x*ws[8] + v2.y*ws[9] + v2.z*ws[10] + v2.w*ws[11];
            const float es1 =
                v3.x*ws[0] + v3.y*ws[1] + v3.z*ws[2]  + v3.w*ws[3] +
                v4.x*ws[4] + v4.y*ws[5] + v4.z*ws[6]  + v4.w*ws[7] +
                v5.x*ws[8] + v5.y*ws[9] + v5.z*ws[10] + v5.w*ws[11];
            const int loc = (tid & 15) * 4 + 2 * c;
            es_loc[loc]     = es0;
            es_loc[loc + 1] = es1;
        }
    }
    __syncthreads();                             // the ONLY barrier

    // ---- softmax over 32 lanes, 4 tasks/thread (no max-subtract, guarded) ----
    float ex[4], sum[4];
    #pragma unroll
    for (int t = 0; t < 4; ++t) {
        float e = es_loc[slot + 16 * t] + edt[jv[t]];
        e = e > 0.f ? e : GAT_ALPHA * e;
        ex[t]  = __expf(fminf(e, 80.f));
        sum[t] = ex[t];
    }
    #pragma unroll
    for (int off = 16; off; off >>= 1) {
        #pragma unroll
        for (int t = 0; t < 4; ++t) sum[t] += __shfl_xor(sum[t], off, 32);
    }
    float att[4];
    #pragma unroll
    for (int t = 0; t < 4; ++t) att[t] = ex[t] / sum[t];

    // ---- dense stores via shfl-remap (validated rounds 3-4) ----
    #pragma unroll
    for (int t = 0; t < 4; ++t) {
        float4* o4 = (float4*)out + (size_t)(pairG0 + 16 * t) * 96;
        #pragma unroll
        for (int r = 0; r < 3; ++r) {
            const int f  = r * 32 + k;
            const int kk = f / 3;
            const int q  = f - 3 * kk;
            const float attk = __shfl(att[t], kk, 32);
            const int   jk   = __shfl(jv[t],  kk, 32);
            const float4 v = *(const float4*)(rows + (size_t)jk * 12 + 4 * q);
            o4[f] = make_float4(attk * v.x, attk * v.y, attk * v.z, attk * v.w);
        }
    }
}

// ---------------- Fallback: verified generic single-kernel path ----------------
__global__ __launch_bounds__(256) void gat_fused(
    const float* __restrict__ x, const float* __restrict__ W,
    const float* __restrict__ a, const int* __restrict__ idx,
    float* __restrict__ out)
{
    __shared__ float wvec[24];
    __shared__ float stage[8 * 384];
    const int tid = threadIdx.x;

    if (tid < 24) {
        const int s = tid % 12;
        const float* av = a + (tid < 12 ? 0 : 12);
        float acc = 0.f;
        #pragma unroll
        for (int t = 0; t < 12; ++t) acc += W[s * 12 + t] * av[t];
        wvec[tid] = acc;
    }
    __syncthreads();

    const int p    = tid >> 5;
    const int pair = blockIdx.x * 8 + p;
    const int k    = tid & 31;

    const float4* rowi = (const float4*)(x + (size_t)pair * 12);
    const float4 i0 = rowi[0], i1 = rowi[1], i2 = rowi[2];
    const float e_src =
        i0.x*wvec[0] + i0.y*wvec[1] + i0.z*wvec[2]  + i0.w*wvec[3] +
        i1.x*wvec[4] + i1.y*wvec[5] + i1.z*wvec[6]  + i1.w*wvec[7] +
        i2.x*wvec[8] + i2.y*wvec[9] + i2.z*wvec[10] + i2.w*wvec[11];

    const int j   = idx[(size_t)pair * 32 + k];
    const int nbr = (pair & ~(GAT_N - 1)) + j;
    const float4* rowj = (const float4*)(x + (size_t)nbr * 12);
    const float4 n0 = rowj[0], n1 = rowj[1], n2 = rowj[2];
    const float e_dst =
        n0.x*wvec[12] + n0.y*wvec[13] + n0.z*wvec[14] + n0.w*wvec[15] +
        n1.x*wvec[16] + n1.y*wvec[17] + n1.z*wvec[18] + n1.w*wvec[19] +
        n2.x*wvec[20] + n2.y*wvec[21] + n2.z*wvec[22] + n2.w*wvec[23];

    float sc = e_src + e_dst;
    sc = sc > 0.f ? sc : GAT_ALPHA * sc;
    float m = sc;
    #pragma unroll
    for (int off = 16; off; off >>= 1) m = fmaxf(m, __shfl_xor(m, off, 32));
    const float ex = __expf(sc - m);
    float sum = ex;
    #pragma unroll
    for (int off = 16; off; off >>= 1) sum += __shfl_xor(sum, off, 32);
    const float att = ex / sum;

    float4* st = (float4*)(stage + p * 384 + k * 12);
    st[0] = make_float4(att * n0.x, att * n0.y, att * n0.z, att * n0.w);
    st[1] = make_float4(att * n1.x, att * n1.y, att * n1.z, att * n1.w);
    st[2] = make_float4(att * n2.x, att * n2.y, att * n2.z, att * n2.w);
    __syncthreads();

    const float4* sm4 = (const float4*)stage;
    float4* o4 = (float4*)(out + (size_t)blockIdx.x * 8 * 384);
    #pragma unroll
    for (int r = 0; r < 3; ++r) o4[tid + 256 * r] = sm4[tid + 256 * r];
}

extern "C" void kernel_launch(void* const* d_in, const int* in_sizes, int n_in,
                              void* d_out, int out_size, void* d_ws, size_t ws_size,
                              hipStream_t stream) {
    // inputs: fushed_features (unused), input_data, W, a, idx
    const float* x   = (const float*)d_in[1];
    const float* W   = (const float*)d_in[2];
    const float* a   = (const float*)d_in[3];
    const int*   idx = (const int*)d_in[4];
    float* out = (float*)d_out;

    const int pairs = in_sizes[1] / 12;    // B*N = 32768 nodes

    if ((pairs & (GAT_N - 1)) == 0) {
        const int blocks = pairs / PPBLK;              // 512 at B=16
        const int swz    = (blocks == 512) ? 1 : 0;    // XCD-affinity valid form
        gat_lds2<<<blocks, THREADS, 0, stream>>>(x, W, a, idx, out, swz);
    } else {
        gat_fused<<<pairs / 8, 256, 0, stream>>>(x, W, a, idx, out);
    }
}